// Round 12
// baseline (81.431 us; speedup 1.0000x reference)
//
#include <hip/hip_runtime.h>

#define SEQ 1024
#define HEADS 16
#define HD 64
#define EMB 1024

typedef short bf16x8 __attribute__((ext_vector_type(8)));
typedef float f32x4 __attribute__((ext_vector_type(4)));

// pack two f32 -> u32 of 2 bf16 (lo = a, hi = b)
static __device__ __forceinline__ unsigned cvtpk(float a, float b) {
  unsigned r;
  asm("v_cvt_pk_bf16_f32 %0, %1, %2" : "=v"(r) : "v"(a), "v"(b));
  return r;
}

static __device__ __forceinline__ float bflo(unsigned u) {
  return __builtin_bit_cast(float, u << 16);
}
static __device__ __forceinline__ float bfhi(unsigned u) {
  return __builtin_bit_cast(float, u & 0xffff0000u);
}

static __device__ __forceinline__ void gload_lds16(const void* g, void* l) {
  __builtin_amdgcn_global_load_lds((const __attribute__((address_space(1))) unsigned int*)g,
                                   (__attribute__((address_space(3))) unsigned int*)l,
                                   16, 0, 0);
}

// ---------------- fused prep + projections (unchanged from r10) ----------------
__global__ __launch_bounds__(256) void k_pp(const int* __restrict__ mask,
                                            const float* __restrict__ Wo,
                                            const float* __restrict__ Wv,
                                            const float* __restrict__ Wq,
                                            const float* __restrict__ Wk,
                                            const float* __restrict__ values,
                                            const float* __restrict__ query,
                                            const float* __restrict__ key,
                                            unsigned long long* __restrict__ mb,
                                            unsigned short* __restrict__ wob,
                                            unsigned short* __restrict__ vb,
                                            unsigned short* __restrict__ qb,
                                            unsigned short* __restrict__ kb) {
  __shared__ unsigned short Wl[64][64];
  const unsigned tid = threadIdx.x;
  const unsigned b = blockIdx.x;

  if (b < 3072) {
    const int lane = tid & 63, c = lane & 15, g = lane >> 4;
    const int wid = b * 4 + (tid >> 6);
    const int t = wid >> 12;
    const int rem = wid & 4095;
    const int n = rem >> 10, h = (rem >> 6) & 15, lb = rem & 63;

    const float* x; unsigned short* out;
    if (t == 0)      { x = values; out = vb; }
    else if (t == 1) { x = query;  out = qb; }
    else             { x = key;    out = kb; }
    const float* Wf = (t == 0) ? Wv : (t == 1) ? Wq : Wk;
    const float sc = (t == 1) ? 0.045084220027786356f : 1.0f;  // log2e/32 for Wq

    {
      const int row = tid >> 2, c0 = (tid & 3) * 16;
      const float4 f0 = *(const float4*)(Wf + row * 64 + c0);
      const float4 f1 = *(const float4*)(Wf + row * 64 + c0 + 4);
      const float4 f2 = *(const float4*)(Wf + row * 64 + c0 + 8);
      const float4 f3 = *(const float4*)(Wf + row * 64 + c0 + 12);
      uint4 u0, u1;
      u0.x = cvtpk(f0.x * sc, f0.y * sc); u0.y = cvtpk(f0.z * sc, f0.w * sc);
      u0.z = cvtpk(f1.x * sc, f1.y * sc); u0.w = cvtpk(f1.z * sc, f1.w * sc);
      u1.x = cvtpk(f2.x * sc, f2.y * sc); u1.y = cvtpk(f2.z * sc, f2.w * sc);
      u1.z = cvtpk(f3.x * sc, f3.y * sc); u1.w = cvtpk(f3.z * sc, f3.w * sc);
      const int s0 = ((c0 >> 3) ^ (row & 7)) << 4;
      const int s1 = (((c0 >> 3) + 1) ^ (row & 7)) << 4;
      *(uint4*)((char*)&Wl[0][0] + row * 128 + s0) = u0;
      *(uint4*)((char*)&Wl[0][0] + row * 128 + s1) = u1;
    }
    __syncthreads();

    bf16x8 bfr[4][2];
    #pragma unroll
    for (int cb = 0; cb < 4; ++cb) {
      const int row = cb * 16 + c;
      #pragma unroll
      for (int ks = 0; ks < 2; ++ks)
        bfr[cb][ks] = *(const bf16x8*)((char*)&Wl[0][0] + row * 128 +
                                       (((ks * 4 + g) ^ (c & 7)) << 4));
    }

    bf16x8 a[2];
    const float* xr = x + ((size_t)n * SEQ + lb * 16 + c) * EMB + h * HD;
    #pragma unroll
    for (int ks = 0; ks < 2; ++ks) {
      const float4 f0 = *(const float4*)(xr + ks * 32 + g * 8);
      const float4 f1 = *(const float4*)(xr + ks * 32 + g * 8 + 4);
      uint4 u;
      u.x = cvtpk(f0.x, f0.y); u.y = cvtpk(f0.z, f0.w);
      u.z = cvtpk(f1.x, f1.y); u.w = cvtpk(f1.z, f1.w);
      a[ks] = __builtin_bit_cast(bf16x8, u);
    }

    f32x4 acc[4] = {};
    #pragma unroll
    for (int cb = 0; cb < 4; ++cb)
      #pragma unroll
      for (int ks = 0; ks < 2; ++ks)
        acc[cb] = __builtin_amdgcn_mfma_f32_16x16x32_bf16(a[ks], bfr[cb][ks], acc[cb], 0, 0, 0);

    if (t == 0) {
      unsigned short* vt = out + (size_t)(n * HEADS + h) * (HD * SEQ);
      const int key0 = lb * 16 + 4 * g;
      #pragma unroll
      for (int cb = 0; cb < 4; ++cb) {
        const unsigned w0 = cvtpk(acc[cb][0], acc[cb][1]);
        const unsigned w1 = cvtpk(acc[cb][2], acc[cb][3]);
        *(uint2*)(vt + (size_t)(cb * 16 + c) * SEQ + key0) = make_uint2(w0, w1);
      }
    } else {
      unsigned short* op = out + ((size_t)(n * HEADS + h) * SEQ + lb * 16) * HD;
      #pragma unroll
      for (int r = 0; r < 4; ++r) {
        const unsigned w0 = cvtpk(acc[0][r], acc[1][r]);
        const unsigned w1 = cvtpk(acc[2][r], acc[3][r]);
        *(uint2*)(op + (4 * g + r) * HD + 4 * c) = make_uint2(w0, w1);
      }
    }
  } else if (b < 7168) {
    const unsigned lane = tid & 63u;
    const unsigned gwb = (b - 3072) * 16u + (tid >> 6) * 4u;
    #pragma unroll
    for (int it = 0; it < 4; ++it) {
      const unsigned gw = gwb + it;
      const int v = mask[(size_t)gw * 64u + lane];
      const unsigned long long bits = __ballot(v != 0);
      if (lane == 0) {
        const unsigned n = gw >> 14, qrow = (gw >> 4) & 1023u, ktile = gw & 15u;
        mb[((size_t)n * 16 + ktile) * 1024 + qrow] = bits;
      }
    }
  } else {
    const unsigned gid = (b - 7168) * 256u + tid;
    const unsigned e = gid >> 8, rem = gid & 255u;
    const unsigned blk = rem >> 4, cc = rem & 15u;
    const float* src = Wo + (size_t)e * 1024 + blk * 64 + cc;
    const unsigned w0 = cvtpk(src[0], src[16]);
    const unsigned w1 = cvtpk(src[32], src[48]);
    *(uint2*)(wob + (size_t)gid * 4) = make_uint2(w0, w1);
  }
}

// ---------------- flash attention: KEY-SPLIT waves, wave-private LDS, no main-loop barriers ----
// block = (n, h, 64 q-rows); wave w owns keys [w*256, w*256+256) in 8 tiles of 32.
// Wave-private 16KB dbuf slot (K 4KB + V 4KB per buf): every staged byte ds_read once.
// Masks register-double-buffered (mnxt loaded BEFORE STG so compiler auto-waits never
// drain the prefetch); one manual vmcnt(12)/iter. Swapped QK^T, in-register P,
// max-free softmax. Cross-wave O/l merge: pairwise bf16 LDS reduction, wave 0 stores.
__global__ __launch_bounds__(256, 2) void k_attn(const unsigned short* __restrict__ qb,
                                                 const unsigned short* __restrict__ kb,
                                                 const unsigned short* __restrict__ vb,
                                                 const unsigned long long* __restrict__ mb,
                                                 unsigned short* __restrict__ ob) {
  const int tid = threadIdx.x;
  const int w = tid >> 6, lane = tid & 63;
  const int c = lane & 15, g = lane >> 4;
  const int bid = blockIdx.x;
  const int nh = bid & 63, q64 = bid >> 6;
  const int n = nh >> 4, h = nh & 15;
  const int qlo = q64 * 64;

  __shared__ char LDSA[65536];
  char* const slot = LDSA + w * 16384;   // wave-private: [buf 0|1] x [K 4KB | V 4KB]

  const size_t nhb = (size_t)(n * HEADS + h) * (SEQ * HD);
  const unsigned short* qp = qb + nhb;
  const char* kpB = (const char*)(kb + nhb) + (size_t)(w * 256) * 128;  // this wave's keys
  const char* vpB = (const char*)(vb + nhb) + (size_t)(w * 256) * 2;    // V^T col offset

  // Q B-frags first (oldest outstanding): qa[grp][ks] = Q[qlo+grp*16+c][dpos ks*32+8g+j]
  bf16x8 qa[4][2];
  #pragma unroll
  for (int grp = 0; grp < 4; ++grp)
    #pragma unroll
    for (int ks = 0; ks < 2; ++ks)
      qa[grp][ks] = *(const bf16x8*)(qp + (size_t)(qlo + grp * 16 + c) * HD + ks * 32 + g * 8);

  // staging source addresses (4 K + 4 V gload_lds per tile)
  const char* kS[4]; const char* vS[4]; int sO[4];
  #pragma unroll
  for (int i = 0; i < 4; ++i) {
    const int off = i * 1024 + lane * 16;
    sO[i] = off;
    // K: rows 128B; LDS row rho holds key kappa(rho)=4*(rho>>4)+8*((rho>>2)&3)+(rho&3)
    const int rho = off >> 7, sl = (off >> 4) & 7;
    const int kap = 4 * (rho >> 4) + 8 * ((rho >> 2) & 3) + (rho & 3);
    kS[i] = kpB + (size_t)kap * 128 + ((sl ^ (rho & 7)) << 4);
    // V: rows 64B ([d][32 keys]); slot-swz ^((d>>1)&3)
    const int d = off >> 6, sl2 = (off >> 4) & 3;
    vS[i] = vpB + (size_t)d * 2048 + ((sl2 ^ ((d >> 1) & 3)) << 4);
  }

  // mask base for this lane: u64 per (n, kt64, qrow=qlo+grp*16+c)
  const char* const mgb = (const char*)mb + ((size_t)(n * 16) * 1024 + qlo + c) * 8;

  bf16x8 ones;
  #pragma unroll
  for (int j = 0; j < 8; ++j) ones[j] = (short)0x3F80;

  f32x4 o[4][4] = {};
  f32x4 lac[4] = {};
  unsigned mcur[4], mnxt[4];

#define STG(buf, t_) do {                                               \
    char* const db_ = slot + (buf) * 8192;                              \
    _Pragma("unroll")                                                   \
    for (int i = 0; i < 4; ++i) {                                       \
      gload_lds16(kS[i] + (size_t)(t_) * 4096, db_ + sO[i]);            \
      gload_lds16(vS[i] + (t_) * 64, db_ + 4096 + sO[i]);               \
    }                                                                   \
  } while (0)

  // prologue: mask(0) into mnxt [4 loads], then STG(0) [8 loads]
  #pragma unroll
  for (int grp = 0; grp < 4; ++grp)
    mnxt[grp] = *(const unsigned*)(mgb + grp * 128 + (size_t)(w * 4) * 8192);
  STG(0, 0);

  for (int t = 0; t < 8; ++t) {
    const int cur = t & 1;
    // consume previous iter's mask regs (compiler auto-wait here retires ONLY mask loads)
    #pragma unroll
    for (int grp = 0; grp < 4; ++grp) mcur[grp] = mnxt[grp];

    if (t < 7) {
      const int ktg1 = w * 8 + t + 1;
      #pragma unroll
      for (int grp = 0; grp < 4; ++grp)
        mnxt[grp] = *(const unsigned*)(mgb + grp * 128 +
                                       (size_t)(ktg1 >> 1) * 8192 + (ktg1 & 1) * 4);
      STG(cur ^ 1, t + 1);
      asm volatile("s_waitcnt vmcnt(12)" ::: "memory");  // tile t + mask(t) done; t+1 in flight
    } else {
      asm volatile("s_waitcnt vmcnt(0)" ::: "memory");
    }
    char* const Kc = slot + cur * 8192;
    char* const Vc = Kc + 4096;

    // K A-frags: kf[sub][ks] lane(c,g) = K[kappa(sub*16+c)][dpos ks*32+8g+j]
    bf16x8 kf[2][2];
    #pragma unroll
    for (int sub = 0; sub < 2; ++sub) {
      const int rho = sub * 16 + c;   // rho&7 == c&7
      #pragma unroll
      for (int ks = 0; ks < 2; ++ks)
        kf[sub][ks] = *(const bf16x8*)(Kc + rho * 128 + (((ks * 4 + g) ^ (c & 7)) << 4));
    }
    // V B-frags: vf[db] lane(c,g) = V[key=8g+j][e=db*16+c]
    bf16x8 vf[4];
    #pragma unroll
    for (int db = 0; db < 4; ++db) {
      const int d = db * 16 + c;
      vf[db] = *(const bf16x8*)(Vc + d * 64 + ((g ^ ((c >> 1) & 3)) << 4));
    }

    #pragma unroll
    for (int grp = 0; grp < 4; ++grp) {
      f32x4 s0 = {}, s1 = {};
      __builtin_amdgcn_s_setprio(1);
      s0 = __builtin_amdgcn_mfma_f32_16x16x32_bf16(kf[0][0], qa[grp][0], s0, 0, 0, 0);
      s0 = __builtin_amdgcn_mfma_f32_16x16x32_bf16(kf[0][1], qa[grp][1], s0, 0, 0, 0);
      s1 = __builtin_amdgcn_mfma_f32_16x16x32_bf16(kf[1][0], qa[grp][0], s1, 0, 0, 0);
      s1 = __builtin_amdgcn_mfma_f32_16x16x32_bf16(kf[1][1], qa[grp][1], s1, 0, 0, 0);
      __builtin_amdgcn_s_setprio(0);

      // softmax numerators -> PV A-frag: elem j of pa <-> key 8g+j
      const unsigned x = mcur[grp] >> (8 * g);
      const float p0 = (x & 1u)   ? __builtin_exp2f(s0[0]) : 0.f;
      const float p1 = (x & 2u)   ? __builtin_exp2f(s0[1]) : 0.f;
      const float p2 = (x & 4u)   ? __builtin_exp2f(s0[2]) : 0.f;
      const float p3 = (x & 8u)   ? __builtin_exp2f(s0[3]) : 0.f;
      const float p4 = (x & 16u)  ? __builtin_exp2f(s1[0]) : 0.f;
      const float p5 = (x & 32u)  ? __builtin_exp2f(s1[1]) : 0.f;
      const float p6 = (x & 64u)  ? __builtin_exp2f(s1[2]) : 0.f;
      const float p7 = (x & 128u) ? __builtin_exp2f(s1[3]) : 0.f;
      const uint4 pu = make_uint4(cvtpk(p0, p1), cvtpk(p2, p3),
                                  cvtpk(p4, p5), cvtpk(p6, p7));
      const bf16x8 pa = __builtin_bit_cast(bf16x8, pu);

      __builtin_amdgcn_s_setprio(1);
      #pragma unroll
      for (int db = 0; db < 4; ++db)
        o[grp][db] = __builtin_amdgcn_mfma_f32_16x16x32_bf16(pa, vf[db], o[grp][db], 0, 0, 0);
      lac[grp] = __builtin_amdgcn_mfma_f32_16x16x32_bf16(pa, ones, lac[grp], 0, 0, 0);
      __builtin_amdgcn_s_setprio(0);
    }
  }
#undef STG

  // ---- cross-wave reduction (max-free softmax => partials merge by ADD) ----
  // O-slot x: LDSA + x*8192 ([d=64 rows][128B], 16B slot swz ^(d&7)); l-slot: LDSA+32768+x*256
  auto storeO = [&](int x) {
    char* const obw = LDSA + x * 8192;
    #pragma unroll
    for (int grp = 0; grp < 4; ++grp) {
      const int slt = grp * 2 + (g >> 1);
      #pragma unroll
      for (int db = 0; db < 4; ++db) {
        const int d = db * 16 + c;
        *(uint2*)(obw + d * 128 + ((slt ^ (d & 7)) << 4) + 8 * (g & 1)) =
            make_uint2(cvtpk(o[grp][db][0], o[grp][db][1]),
                       cvtpk(o[grp][db][2], o[grp][db][3]));
      }
    }
    if (c == 0) {
      float* const lw = (float*)(LDSA + 32768 + x * 256);
      #pragma unroll
      for (int grp = 0; grp < 4; ++grp)
        *(f32x4*)(lw + grp * 16 + 4 * g) = lac[grp];
    }
  };
  auto loadO = [&](int x) {
    const char* const obr = LDSA + x * 8192;
    #pragma unroll
    for (int grp = 0; grp < 4; ++grp) {
      const int slt = grp * 2 + (g >> 1);
      #pragma unroll
      for (int db = 0; db < 4; ++db) {
        const int d = db * 16 + c;
        const uint2 u = *(const uint2*)(obr + d * 128 + ((slt ^ (d & 7)) << 4) + 8 * (g & 1));
        o[grp][db][0] += bflo(u.x); o[grp][db][1] += bfhi(u.x);
        o[grp][db][2] += bflo(u.y); o[grp][db][3] += bfhi(u.y);
      }
    }
    const float* const lr = (const float*)(LDSA + 32768 + x * 256);
    #pragma unroll
    for (int grp = 0; grp < 4; ++grp)
      lac[grp] += *(const f32x4*)(lr + grp * 16 + 4 * g);
  };

  __syncthreads();
  if (w & 1) storeO(w);                    // waves 1,3 -> slots 1,3
  __syncthreads();
  if (w == 0) loadO(1);                    // w0 += w1
  if (w == 2) { loadO(3); storeO(2); }     // w2 += w3, write to slot 2
  __syncthreads();
  if (w == 0) {
    loadO(2);                              // w0 += (w2+w3)
    #pragma unroll
    for (int grp = 0; grp < 4; ++grp)
      #pragma unroll
      for (int r = 0; r < 4; ++r) {
        const float inv = 1.0f / lac[grp][r];
        const unsigned w0 = cvtpk(o[grp][0][r] * inv, o[grp][1][r] * inv);
        const unsigned w1 = cvtpk(o[grp][2][r] * inv, o[grp][3][r] * inv);
        *(uint2*)(ob + ((size_t)n * SEQ + qlo + grp * 16 + 4 * g + r) * EMB +
                  h * 64 + 4 * c) = make_uint2(w0, w1);
      }
  }
}

// ---------------- out-proj GEMM (unchanged from r10) ----------------
__global__ __launch_bounds__(256, 2) void k_gemm(const unsigned short* __restrict__ A,
                                                 const unsigned short* __restrict__ B,
                                                 const float* __restrict__ bo,
                                                 float* __restrict__ C) {
  const int tid = threadIdx.x;
  const int w = tid >> 6, lane = tid & 63;
  const int c = lane & 15, g = lane >> 4;
  const int bm = blockIdx.x & 31, bn = blockIdx.x >> 5;
  const int m0 = bm * 128, n0 = bn * 64;

  __shared__ unsigned short As[2][128][64];
  __shared__ unsigned short Bs[2][64][64];

  const char* aSrc[4]; int aOff[4];
  const char* bSrc[2]; int bOff[2];
  #pragma unroll
  for (int i = 0; i < 4; ++i) {
    const int off = i * 4096 + tid * 16;
    const int row = off >> 7, slot = (off >> 4) & 7;
    const int sw = (slot ^ (row & 7)) << 4;
    aSrc[i] = (const char*)A + (size_t)(m0 + row) * 2048 + sw;
    aOff[i] = off;
  }
  #pragma unroll
  for (int i = 0; i < 2; ++i) {
    const int off = i * 4096 + tid * 16;
    const int row = off >> 7, slot = (off >> 4) & 7;
    const int sw = (slot ^ (row & 7)) << 4;
    bSrc[i] = (const char*)B + (size_t)(n0 + row) * 2048 + sw;
    bOff[i] = off;
  }

  f32x4 acc[2][4] = {};

#define STAGE(buf, kt_) do {                                                  \
    _Pragma("unroll")                                                         \
    for (int i = 0; i < 4; ++i)                                               \
      gload_lds16(aSrc[i] + (kt_) * 128, (char*)&As[buf][0][0] + aOff[i]);    \
    _Pragma("unroll")                                                         \
    for (int i = 0; i < 2; ++i)                                               \
      gload_lds16(bSrc[i] + (kt_) * 128, (char*)&Bs[buf][0][0] + bOff[i]);    \
  } while (0)

  STAGE(0, 0);

  for (int kt = 0; kt < 16; ++kt) {
    const int cur = kt & 1;
    if (kt < 15) {
      STAGE(cur ^ 1, kt + 1);
      asm volatile("s_waitcnt vmcnt(6)" ::: "memory");
    } else {
      asm volatile("s_waitcnt vmcnt(0)" ::: "memory");
    }
    asm volatile("s_barrier" ::: "memory");

    #pragma unroll
    for (int ks = 0; ks < 2; ++ks) {
      bf16x8 af[2], bf_[4];
      #pragma unroll
      for (int i = 0; i < 2; ++i) {
        const int row = w * 32 + i * 16 + c;
        af[i] = *(const bf16x8*)((char*)&As[cur][0][0] + row * 128 +
                                 (((ks * 4 + g) ^ (c & 7)) << 4));
      }
      #pragma unroll
      for (int j = 0; j < 4; ++j) {
        const int row = j * 16 + c;
        bf_[j] = *(const bf16x8*)((char*)&Bs[cur][0][0] + row * 128 +
                                  (((ks * 4 + g) ^ (c & 7)) << 4));
      }
      __builtin_amdgcn_s_setprio(1);
      #pragma unroll
      for (int i = 0; i < 2; ++i)
        #pragma unroll
        for (int j = 0; j < 4; ++j)
          acc[i][j] = __builtin_amdgcn_mfma_f32_16x16x32_bf16(af[i], bf_[j], acc[i][j], 0, 0, 0);
      __builtin_amdgcn_s_setprio(0);
    }

    if (kt < 15) asm volatile("s_barrier" ::: "memory");
  }
#undef STAGE

  #pragma unroll
  for (int j = 0; j < 4; ++j) {
    const int col = n0 + j * 16 + c;
    const float bv = bo[col];
    #pragma unroll
    for (int i = 0; i < 2; ++i) {
      const int rowb = m0 + w * 32 + i * 16 + 4 * g;
      #pragma unroll
      for (int r = 0; r < 4; ++r)
        C[(size_t)(rowb + r) * 1024 + col] = acc[i][j][r] + bv;
    }
  }
}

extern "C" void kernel_launch(void* const* d_in, const int* in_sizes, int n_in,
                              void* d_out, int out_size, void* d_ws, size_t ws_size,
                              hipStream_t stream) {
  const float* values = (const float*)d_in[0];
  const float* query  = (const float*)d_in[1];
  const float* key    = (const float*)d_in[2];
  const int*   mask   = (const int*)d_in[3];
  const float* Wv     = (const float*)d_in[4];
  const float* Wk     = (const float*)d_in[5];
  const float* Wq     = (const float*)d_in[6];
  const float* Wo     = (const float*)d_in[7];
  const float* bo     = (const float*)d_in[8];
  float* out = (float*)d_out;

  char* ws = (char*)d_ws;
  unsigned short* qb = (unsigned short*)(ws);                            // 8MB  [N][H][S][Dpi]
  unsigned short* kb = (unsigned short*)(ws + (size_t)8 * 1024 * 1024);  // 8MB  [N][H][S][Dpi]
  unsigned short* vb = (unsigned short*)(ws + (size_t)16 * 1024 * 1024); // 8MB  V^T [N][H][D][S]
  unsigned short* ob = (unsigned short*)(ws + (size_t)24 * 1024 * 1024); // 8MB  [N][S][Epi]
  unsigned long long* mb = (unsigned long long*)(ws + (size_t)32 * 1024 * 1024);   // 512KB
  unsigned short* wob = (unsigned short*)(ws + (size_t)33 * 1024 * 1024);          // 2MB

  k_pp<<<8192, 256, 0, stream>>>(mask, Wo, Wv, Wq, Wk, values, query, key, mb, wob, vb, qb, kb);
  k_attn<<<1024, 256, 0, stream>>>(qb, kb, vb, mb, ob);
  k_gemm<<<512, 256, 0, stream>>>(ob, wob, bo, out);
}